// Round 14
// baseline (365.588 us; speedup 1.0000x reference)
//
#include <hip/hip_runtime.h>
#include <hip/hip_bf16.h>

#define NN 8192
#define EE 131072
#define GG 32
#define FF 64
#define DDIM 128
#define NB 8
#define SH 9
#define RMAX 2.03f
#define INV_AVG (1.0f/16.0f)

typedef __attribute__((ext_vector_type(8))) short short8v;
typedef __attribute__((ext_vector_type(4))) float float4v;

// fast softplus: ln2 * log2(1 + 2^(x*log2e)); exact limit for large x
__device__ __forceinline__ float softplus_f(float v){
  float t = exp2f(v*1.44269504f);
  float r = 0.69314718f*log2f(1.0f+t);
  return (v > 80.0f) ? v : r;
}
__device__ __forceinline__ unsigned short f2bf(float f){
  __hip_bfloat16 h = __float2bfloat16(f);
  return *reinterpret_cast<unsigned short*>(&h);
}
__device__ __forceinline__ float bf2f(unsigned short h){
  return __uint_as_float(((unsigned int)h)<<16);
}

// ---------------- CSR build ----------------
__global__ __launch_bounds__(256) void k_deg(const int* __restrict__ rcv, int* __restrict__ deg)
{
  int e = blockIdx.x*256 + threadIdx.x;
  if (e < EE) atomicAdd(&deg[rcv[e]], 1);
}

__global__ __launch_bounds__(256) void k_scan(const int* __restrict__ deg,
                                              int* __restrict__ off, int* __restrict__ cur)
{
  __shared__ int part[256];
  int t = threadIdx.x;
  int base = t*32;
  int s = 0;
  for (int i=0;i<32;i++) s += deg[base+i];
  part[t] = s;
  __syncthreads();
  for (int o2=1;o2<256;o2<<=1){
    int v = (t>=o2)? part[t-o2] : 0;
    __syncthreads();
    part[t] += v;
    __syncthreads();
  }
  int run = part[t]-s;
  for (int i=0;i<32;i++){
    off[base+i]=run; cur[base+i]=run;
    run += deg[base+i];
  }
  if (t==255) off[NN]=run;
}

__global__ __launch_bounds__(256) void k_fill(const int* __restrict__ rcv,
                                              int* __restrict__ cur, int* __restrict__ eidx)
{
  int e = blockIdx.x*256 + threadIdx.x;
  if (e < EE){
    int p = atomicAdd(&cur[rcv[e]], 1);
    eidx[p] = e;
  }
}

// ---------------- merged: sorted geometry (blocks 0..511) + x init (512..767) ----------------
__global__ __launch_bounds__(256) void k_prep(
    const float* __restrict__ pos, const int* __restrict__ snd, const int* __restrict__ rcv,
    const int* __restrict__ eidx, const int* __restrict__ spec, const float* __restrict__ et,
    float* __restrict__ Yb, float* __restrict__ Bb, float* __restrict__ Eb,
    int* __restrict__ snds, float* __restrict__ x)
{
  int b = blockIdx.x;
  if (b < 512){
    int j = b*256 + threadIdx.x;
    int e = eidx[j];
    int s = snd[e], r = rcv[e];
    snds[j] = s;
    float dx = pos[3*r  ]-pos[3*s  ];
    float dy = pos[3*r+1]-pos[3*s+1];
    float dz = pos[3*r+2]-pos[3*s+2];
    float d  = sqrtf(dx*dx+dy*dy+dz*dz);
    float dsafe = fmaxf(d, 1e-9f);
    float inv = 1.0f/dsafe;
    float xx = dx*inv, yy = dy*inv, zz = dz*inv;
    const float c1=1.7320508075688772f, c2=3.872983346207417f, c3=1.118033988749895f;
    float Y[SH];
    Y[0]=1.0f; Y[1]=c1*xx; Y[2]=c1*yy; Y[3]=c1*zz;
    Y[4]=c2*xx*yy; Y[5]=c2*yy*zz; Y[6]=c3*(3.0f*zz*zz-1.0f); Y[7]=c2*xx*zz; Y[8]=0.5f*c2*(xx*xx-yy*yy);
    #pragma unroll
    for (int i=0;i<SH;i++) Yb[(size_t)j*SH+i]=Y[i];
    float sc = sqrtf(2.0f/RMAX)*inv;
    float th = 3.14159265358979f*dsafe/RMAX;
    float s1 = sinf(th), cth = cosf(th);
    float skm = 0.0f, sk = s1, twoc = 2.0f*cth;
    #pragma unroll
    for (int k=0;k<NB;k++){
      Bb[(size_t)j*NB+k] = sc*sk;
      float sn = twoc*sk - skm;
      skm = sk; sk = sn;
    }
    float tt = fminf(d/RMAX, 1.0f-1e-6f);
    Eb[j] = (d < RMAX) ? exp2f(-1.44269504f*tt*tt/(1.0f-tt*tt)) : 0.0f;
  } else {
    int i0 = ((b-512)*256 + threadIdx.x)*8;
    int n = i0 >> 6, f0 = i0 & 63;
    const float4v* src = (const float4v*)(et + (size_t)spec[n]*FF + f0);
    float4v v0 = src[0], v1 = src[1];
    *(float4v*)(x+i0)   = v0;
    *(float4v*)(x+i0+4) = v1;
  }
}

// ---------------- weight pack: W2 (blocks 0..95) ----------------
// Bp[((li*12+t)*2+s)*64*8 + l*8 + j] = W2[li][k][3f+c], k=s*32+(l>>4)*8+j,
// col'=t*16+(l&15), f=col'&63, c=col'>>6
__global__ __launch_bounds__(256) void k_pack(
    const float* __restrict__ W2, const float* __restrict__ Wr,
    unsigned short* __restrict__ Bp, unsigned short* __restrict__ Wrp)
{
  int b = blockIdx.x;
  if (b < 96){
    int id = b*256 + threadIdx.x;               // 24576
    int j  = id & 7;
    int l  = (id>>3) & 63;
    int s  = (id>>9) & 1;
    int rem = id >> 10;
    int t  = rem % 12;
    int li = rem / 12;
    int k  = s*32 + (l>>4)*8 + j;
    int colp = t*16 + (l&15);
    int f = colp & 63, c = colp >> 6;
    Bp[id] = f2bf(W2[(size_t)li*FF*192 + k*192 + 3*f + c]);
  } else {
    int id = (b-96)*256 + threadIdx.x;          // 147456
    int j  = id & 7;
    int l  = (id>>3) & 63;
    int t  = (id>>9) & 7;
    int rem = id >> 12;
    int ks = rem % 18;
    int li = rem / 18;
    int k  = ks*32 + (l>>4)*8 + j;
    int col = t*16 + (l&15);
    Wrp[id] = f2bf(Wr[(size_t)li*576*DDIM + k*DDIM + col]);
  }
}

// ---------------- FUSED edge-MLP (MFMA) + gather: one wave per node ----------------
// No LDS B-staging (global L2-broadcast loads), fast softplus, register acc.
__global__ __launch_bounds__(256) void k_fused2(
  const float* __restrict__ Bb, const float* __restrict__ Eb, const float* __restrict__ Yb,
  const int* __restrict__ snds, const int* __restrict__ off,
  const float* __restrict__ x, const float* __restrict__ W1l,
  const unsigned short* __restrict__ Bpl,
  unsigned short* __restrict__ aggb, float* __restrict__ c0)
{
  __shared__ float sW1[NB*FF];        // 2 KB
  __shared__ float sStage[4][580];    // 9.3 KB
  int tid = threadIdx.x;
  for (int i=tid;i<NB*FF;i+=256) sW1[i]=W1l[i];
  __syncthreads();

  int lane = tid & 63, wv = tid >> 6;
  int n = blockIdx.x*4 + wv;
  int js = off[n], je = off[n+1];
  int mrow = lane & 15, kg = lane >> 4;

  float acc[4][9];
  #pragma unroll
  for (int fg=0;fg<4;fg++)
    #pragma unroll
    for (int q=0;q<9;q++) acc[fg][q]=0.0f;

  for (int t0 = js; t0 < je; t0 += 16){
    // ---- A-fragment: H row for edge t0+mrow (env/16 folded in; invalid rows -> 0) ----
    int row = t0 + mrow;
    bool v = row < je;
    float B8[8];
    float es = 0.0f;
    if (v){
      const float4v* bp = (const float4v*)(Bb + (size_t)row*NB);
      float4v b0v = bp[0], b1v = bp[1];
      B8[0]=b0v[0];B8[1]=b0v[1];B8[2]=b0v[2];B8[3]=b0v[3];
      B8[4]=b1v[0];B8[5]=b1v[1];B8[6]=b1v[2];B8[7]=b1v[3];
      es = Eb[row]*INV_AVG;
    } else {
      #pragma unroll
      for (int b=0;b<8;b++) B8[b]=0.0f;
    }
    short8v a0, a1;
    #pragma unroll
    for (int j=0;j<8;j++){
      int kc = kg*8 + j;
      float h0=0.0f, h1=0.0f;
      #pragma unroll
      for (int b=0;b<NB;b++){
        h0 += B8[b]*sW1[b*FF + kc];
        h1 += B8[b]*sW1[b*FF + kc + 32];
      }
      a0[j] = (short)f2bf(softplus_f(h0)*es);
      a1[j] = (short)f2bf(softplus_f(h1)*es);
    }
    // ---- per-row x values for this kg-group's 4 rows ----
    int rc[4];
    float xv[4][4];
    #pragma unroll
    for (int i=0;i<4;i++){
      int r2 = t0 + kg*4 + i;
      rc[i] = (r2 < je) ? r2 : js;          // clamped; contribution is 0 via zero A-rows
      int xs = snds[rc[i]];
      #pragma unroll
      for (int fg=0;fg<4;fg++) xv[i][fg] = x[(size_t)xs*FF + fg*16 + mrow];
    }
    // ---- 12 MFMA tiles: c = component group, fg = feature group ----
    #pragma unroll
    for (int c=0;c<3;c++){
      const int sh0 = (c==0)?0:(c==1)?1:4;
      const int nsh = (c==0)?1:(c==1)?3:5;
      float ys[4][5];
      #pragma unroll
      for (int i=0;i<4;i++){
        const float* y = Yb + (size_t)rc[i]*SH;
        #pragma unroll
        for (int q=0;q<5;q++) ys[i][q] = (q<nsh) ? y[sh0+q] : 0.0f;
      }
      #pragma unroll
      for (int fg=0;fg<4;fg++){
        int t = c*4 + fg;
        short8v b0 = *(const short8v*)(Bpl + ((size_t)(t*2+0)*64 + lane)*8);
        short8v b1 = *(const short8v*)(Bpl + ((size_t)(t*2+1)*64 + lane)*8);
        float4v o4 = {0.0f,0.0f,0.0f,0.0f};
        o4 = __builtin_amdgcn_mfma_f32_16x16x32_bf16(a0, b0, o4, 0, 0, 0);
        o4 = __builtin_amdgcn_mfma_f32_16x16x32_bf16(a1, b1, o4, 0, 0, 0);
        #pragma unroll
        for (int i=0;i<4;i++){
          float p = o4[i]*xv[i][fg];
          #pragma unroll
          for (int q=0;q<5;q++)
            if (q<nsh) acc[fg][sh0+q] += ys[i][q]*p;
        }
      }
    }
  }

  // ---- reduce across the 4 kg lane-groups ----
  #pragma unroll
  for (int fg=0;fg<4;fg++)
    #pragma unroll
    for (int q=0;q<9;q++){
      float vv = acc[fg][q];
      vv += __shfl_xor(vv, 16, 64);
      vv += __shfl_xor(vv, 32, 64);
      acc[fg][q] = vv;
    }
  if (kg == 0){
    #pragma unroll
    for (int fg=0;fg<4;fg++)
      #pragma unroll
      for (int q=0;q<9;q++)
        sStage[wv][(fg*16 + mrow)*9 + q] = acc[fg][q];
  }
  __syncthreads();
  unsigned short* db = aggb + (size_t)n*576 + lane*SH;
  #pragma unroll
  for (int q=0;q<9;q++) db[q] = f2bf(sStage[wv][lane*9 + q]);
  c0[(size_t)n*FF + lane] = sStage[wv][lane*9];
}

// ---------------- readout via MFMA: emb[:, colOff:+128] = aggb @ Wrp ----------------
__global__ __launch_bounds__(128) void k_read_mfma(
    const unsigned short* __restrict__ aggb, const unsigned short* __restrict__ Wrpl,
    float* __restrict__ emb, int colOff)
{
  int tid = threadIdx.x;
  int lane = tid & 63, wv = tid >> 6;
  int r0 = (blockIdx.x*2 + wv)*16;
  int mrow = lane & 15, kgrp = lane >> 4;
  float4v acc[8];
  #pragma unroll
  for (int t=0;t<8;t++){ acc[t][0]=0.f; acc[t][1]=0.f; acc[t][2]=0.f; acc[t][3]=0.f; }
  const unsigned short* arow = aggb + (size_t)(r0+mrow)*576 + kgrp*8;
  #pragma unroll 3
  for (int ks=0; ks<18; ++ks){
    short8v a = *(const short8v*)(arow + ks*32);
    #pragma unroll
    for (int t=0;t<8;t++){
      short8v b = *(const short8v*)(Wrpl + (((size_t)ks*8+t)*64 + lane)*8);
      acc[t] = __builtin_amdgcn_mfma_f32_16x16x32_bf16(a, b, acc[t], 0, 0, 0);
    }
  }
  #pragma unroll
  for (int t=0;t<8;t++){
    #pragma unroll
    for (int i=0;i<4;i++){
      emb[(size_t)(r0 + kgrp*4 + i)*256 + colOff + t*16 + mrow] = acc[t][i];
    }
  }
}

// ---------------- node update: x = silu(c0@W_upd + x@W_self) ----------------
__global__ __launch_bounds__(256) void k_upd(
    const float* __restrict__ c0, const float* __restrict__ xin,
    const float* __restrict__ Wu, const float* __restrict__ Wsf, float* __restrict__ xout)
{
  __shared__ float sWu[FF*FF], sWs[FF*FF];
  __shared__ float sA[4][FF], sX[4][FF];
  int t = threadIdx.x;
  for (int i=t;i<FF*FF;i+=256){ sWu[i]=Wu[i]; sWs[i]=Wsf[i]; }
  int lane = t&63, wv = t>>6;
  int n = blockIdx.x*4 + wv;
  sA[wv][lane] = c0[(size_t)n*FF + lane];
  sX[wv][lane] = xin[n*FF + lane];
  __syncthreads();
  float a=0.0f;
  #pragma unroll 8
  for (int k=0;k<FF;k++) a += sA[wv][k]*sWu[k*FF+lane] + sX[wv][k]*sWs[k*FF+lane];
  float sg = 1.0f/(1.0f+exp2f(-1.44269504f*a));
  xout[n*FF+lane] = a*sg;
}

// ---------------- merged heads ----------------
__global__ __launch_bounds__(256) void k_heads(
    const float* __restrict__ emb, const float* __restrict__ wf,
    const int* __restrict__ nnode, const int* __restrict__ tspec,
    const float* __restrict__ Ws1, const float* __restrict__ Ws2,
    const float* __restrict__ stab, const float* __restrict__ Wpos,
    float* __restrict__ outF, float* __restrict__ outSp, float* __restrict__ outPos)
{
  int b = blockIdx.x, t = threadIdx.x;
  if (b < 2048){
    int lane = t&63, wv = t>>6;
    int n = b*4 + wv;
    float a=0.0f;
    #pragma unroll
    for (int j=0;j<4;j++) a += emb[(size_t)n*256 + j*64 + lane]*wf[j*64+lane];
    #pragma unroll
    for (int off=32; off>0; off>>=1) a += __shfl_down(a, off, 64);
    if (lane==0) outF[n]=a;
  } else if (b < 2080){
    __shared__ float sf[256], sh2[128];
    int g = b - 2048;
    int fi = 0;
    for (int i=0;i<g;i++) fi += nnode[i];
    sf[t] = emb[(size_t)fi*256 + t];
    __syncthreads();
    if (t < 128){
      float a=0.0f;
      #pragma unroll 4
      for (int k=0;k<256;k++) a += sf[k]*Ws1[k*128+t];
      sh2[t] = softplus_f(a);
    }
    __syncthreads();
    if (t < 5){
      float a=0.0f;
      for (int k=0;k<128;k++) a += sh2[k]*Ws2[k*5+t];
      outSp[g*5+t]=a;
    }
  } else {
    __shared__ float ssp[256];
    int pb = b - 2080;
    int g = pb >> 2;
    int p = (pb & 3)*256 + t;
    int fi = 0;
    for (int i=0;i<g;i++) fi += nnode[i];
    int ts = tspec[g];
    ssp[t] = emb[(size_t)fi*256 + t]*stab[(size_t)ts*256 + t];
    __syncthreads();
    float a=0.0f;
    #pragma unroll 4
    for (int k=0;k<256;k++) a += ssp[k]*Wpos[(size_t)k*1024 + p];
    outPos[(size_t)g*1024 + p] = a;
  }
}

extern "C" void kernel_launch(void* const* d_in, const int* in_sizes, int n_in,
                              void* d_out, int out_size, void* d_ws, size_t ws_size,
                              hipStream_t stream)
{
  const float* positions = (const float*)d_in[0];
  const int*   species   = (const int*)  d_in[1];
  const int*   senders   = (const int*)  d_in[2];
  const int*   receivers = (const int*)  d_in[3];
  const int*   n_node    = (const int*)  d_in[4];
  const int*   tspec     = (const int*)  d_in[5];
  const float* emb_table = (const float*)d_in[6];
  const float* W1        = (const float*)d_in[7];
  const float* W2        = (const float*)d_in[8];
  const float* W_self    = (const float*)d_in[9];
  const float* W_upd     = (const float*)d_in[10];
  const float* W_read    = (const float*)d_in[11];
  const float* w_focus   = (const float*)d_in[12];
  const float* Ws1       = (const float*)d_in[13];
  const float* Ws2       = (const float*)d_in[14];
  const float* stab      = (const float*)d_in[15];
  const float* W_pos     = (const float*)d_in[16];

  char* base = (char*)d_ws;
  size_t ofs = 0;
  auto alloc = [&](size_t bytes)->char*{
    char* p = base + ofs;
    ofs = (ofs + bytes + 255) & ~(size_t)255;
    return p;
  };
  float* Yb   = (float*)alloc((size_t)EE*SH*4);      // sorted
  float* Bb   = (float*)alloc((size_t)EE*NB*4);      // sorted
  float* Eb   = (float*)alloc((size_t)EE*4);         // sorted
  int*   snds = (int*)  alloc((size_t)EE*4);         // sorted senders
  float* xA   = (float*)alloc((size_t)NN*FF*4);
  float* xB   = (float*)alloc((size_t)NN*FF*4);
  float* c0   = (float*)alloc((size_t)NN*FF*4);
  float* emb  = (float*)alloc((size_t)NN*256*4);
  int*   deg  = (int*)  alloc((size_t)NN*4);
  int*   off  = (int*)  alloc((size_t)(NN+1)*4);
  int*   cur  = (int*)  alloc((size_t)NN*4);
  int*   eidx = (int*)  alloc((size_t)EE*4);
  unsigned short* aggb = (unsigned short*)alloc((size_t)NN*576*2);
  unsigned short* Bp   = (unsigned short*)alloc((size_t)2*12*2*64*8*2);
  unsigned short* Wrp  = (unsigned short*)alloc((size_t)2*18*8*64*8*2);

  float* outFocus = (float*)d_out;
  float* outSp    = outFocus + NN;
  float* outPos   = outSp + GG*5;

  // CSR + prep + packs
  (void)hipMemsetAsync(deg, 0, NN*sizeof(int), stream);
  k_deg<<<EE/256,256,0,stream>>>(receivers,deg);
  k_scan<<<1,256,0,stream>>>(deg,off,cur);
  k_fill<<<EE/256,256,0,stream>>>(receivers,cur,eidx);
  k_prep<<<768,256,0,stream>>>(positions,senders,receivers,eidx,species,emb_table,
                               Yb,Bb,Eb,snds,xA);
  k_pack<<<672,256,0,stream>>>(W2,W_read,Bp,Wrp);

  // ---- layer 0 ----
  k_fused2<<<NN/4,256,0,stream>>>(Bb,Eb,Yb,snds,off,xA,W1,Bp,aggb,c0);
  k_read_mfma<<<NN/32,128,0,stream>>>(aggb,Wrp,emb,0);
  k_upd<<<NN/4,256,0,stream>>>(c0,xA,W_upd,W_self,xB);

  // ---- layer 1 ----
  k_fused2<<<NN/4,256,0,stream>>>(Bb,Eb,Yb,snds,off,xB,W1+NB*FF,Bp+(size_t)12*2*64*8,aggb,c0);
  k_read_mfma<<<NN/32,128,0,stream>>>(aggb,Wrp+(size_t)18*8*64*8,emb,DDIM);

  // ---- heads ----
  k_heads<<<2208,256,0,stream>>>(emb,w_focus,n_node,tspec,Ws1,Ws2,stab,W_pos,
                                 outFocus,outSp,outPos);
}

// Round 17
// 253.625 us; speedup vs baseline: 1.4414x; 1.4414x over previous
//
#include <hip/hip_runtime.h>
#include <hip/hip_bf16.h>

#define NN 8192
#define EE 131072
#define GG 32
#define FF 64
#define DDIM 128
#define NB 8
#define SH 9
#define RMAX 2.03f
#define INV_AVG (1.0f/16.0f)
#define TABN 2048   // intervals; table rows 0..TABN (2049 rows) per layer

typedef __attribute__((ext_vector_type(8))) short short8v;
typedef __attribute__((ext_vector_type(4))) float float4v;

// fast softplus: ln2 * log2(1 + 2^(x*log2e)); exact limit for large x
__device__ __forceinline__ float softplus_f(float v){
  float t = exp2f(v*1.44269504f);
  float r = 0.69314718f*log2f(1.0f+t);
  return (v > 80.0f) ? v : r;
}
__device__ __forceinline__ unsigned short f2bf(float f){
  __hip_bfloat16 h = __float2bfloat16(f);
  return *reinterpret_cast<unsigned short*>(&h);
}
__device__ __forceinline__ float bf2f(unsigned short h){
  return __uint_as_float(((unsigned int)h)<<16);
}

// ---------------- CSR build ----------------
__global__ __launch_bounds__(256) void k_deg(const int* __restrict__ rcv, int* __restrict__ deg)
{
  int e = blockIdx.x*256 + threadIdx.x;
  if (e < EE) atomicAdd(&deg[rcv[e]], 1);
}

__global__ __launch_bounds__(256) void k_scan(const int* __restrict__ deg,
                                              int* __restrict__ off, int* __restrict__ cur)
{
  __shared__ int part[256];
  int t = threadIdx.x;
  int base = t*32;
  int s = 0;
  for (int i=0;i<32;i++) s += deg[base+i];
  part[t] = s;
  __syncthreads();
  for (int o2=1;o2<256;o2<<=1){
    int v = (t>=o2)? part[t-o2] : 0;
    __syncthreads();
    part[t] += v;
    __syncthreads();
  }
  int run = part[t]-s;
  for (int i=0;i<32;i++){
    off[base+i]=run; cur[base+i]=run;
    run += deg[base+i];
  }
  if (t==255) off[NN]=run;
}

__global__ __launch_bounds__(256) void k_fill(const int* __restrict__ rcv,
                                              int* __restrict__ cur, int* __restrict__ eidx)
{
  int e = blockIdx.x*256 + threadIdx.x;
  if (e < EE){
    int p = atomicAdd(&cur[rcv[e]], 1);
    eidx[p] = e;
  }
}

// ---------------- merged: sorted geometry (blocks 0..511) + x init (512..767) ----------------
// writes Y (sorted), u = d*2048/RMAX (sorted), snds (sorted), xA
__global__ __launch_bounds__(256) void k_prep(
    const float* __restrict__ pos, const int* __restrict__ snd, const int* __restrict__ rcv,
    const int* __restrict__ eidx, const int* __restrict__ spec, const float* __restrict__ et,
    float* __restrict__ Yb, float* __restrict__ ub,
    int* __restrict__ snds, float* __restrict__ x)
{
  int b = blockIdx.x;
  if (b < 512){
    int j = b*256 + threadIdx.x;
    int e = eidx[j];
    int s = snd[e], r = rcv[e];
    snds[j] = s;
    float dx = pos[3*r  ]-pos[3*s  ];
    float dy = pos[3*r+1]-pos[3*s+1];
    float dz = pos[3*r+2]-pos[3*s+2];
    float d  = sqrtf(dx*dx+dy*dy+dz*dz);
    float dsafe = fmaxf(d, 1e-9f);
    float inv = 1.0f/dsafe;
    float xx = dx*inv, yy = dy*inv, zz = dz*inv;
    const float c1=1.7320508075688772f, c2=3.872983346207417f, c3=1.118033988749895f;
    float Y[SH];
    Y[0]=1.0f; Y[1]=c1*xx; Y[2]=c1*yy; Y[3]=c1*zz;
    Y[4]=c2*xx*yy; Y[5]=c2*yy*zz; Y[6]=c3*(3.0f*zz*zz-1.0f); Y[7]=c2*xx*zz; Y[8]=0.5f*c2*(xx*xx-yy*yy);
    #pragma unroll
    for (int i=0;i<SH;i++) Yb[(size_t)j*SH+i]=Y[i];
    // table coordinate; clamp so i+1 <= TABN always
    float u = fminf(d*((float)TABN/RMAX), 2047.999f);
    ub[j] = u;
  } else {
    int i0 = ((b-512)*256 + threadIdx.x)*8;
    int n = i0 >> 6, f0 = i0 & 63;
    const float4v* src = (const float4v*)(et + (size_t)spec[n]*FF + f0);
    float4v v0 = src[0], v1 = src[1];
    *(float4v*)(x+i0)   = v0;
    *(float4v*)(x+i0+4) = v1;
  }
}

// ---------------- pack W_read (both layers) into MFMA B-frag layout ----------------
__global__ __launch_bounds__(256) void k_pack(
    const float* __restrict__ Wr, unsigned short* __restrict__ Wrp)
{
  int id = blockIdx.x*256 + threadIdx.x;      // 147456
  int j  = id & 7;
  int l  = (id>>3) & 63;
  int t  = (id>>9) & 7;
  int rem = id >> 12;
  int ks = rem % 18;
  int li = rem / 18;
  int k  = ks*32 + (l>>4)*8 + j;
  int col = t*16 + (l&15);
  Wrp[id] = f2bf(Wr[(size_t)li*576*DDIM + k*DDIM + col]);
}

// ---------------- build O(d) lookup table: T[li][row][c*64+f] ----------------
// row r: d = r*RMAX/TABN; O = (softplus(basis@W1)*env/16) @ W2, cols permuted (c*64+f <-> 3f+c)
// grid: 2 layers * 513 blocks, 4 rows/block
__global__ __launch_bounds__(256) void k_tab(
    const float* __restrict__ W1, const float* __restrict__ W2,
    unsigned short* __restrict__ Tb)
{
  __shared__ float sW1[NB*FF];    // 2 KB
  __shared__ float sW2[FF*192];   // 48 KB
  __shared__ float sH[4][FF];     // 1 KB
  int li = blockIdx.x / 513;
  int rb = (blockIdx.x % 513) * 4;
  int tid = threadIdx.x, lane = tid & 63, wv = tid >> 6;
  const float* W1l = W1 + li*NB*FF;
  const float* W2l = W2 + (size_t)li*FF*192;
  for (int i=tid;i<NB*FF;i+=256)  sW1[i]=W1l[i];
  for (int i=tid;i<FF*192;i+=256) sW2[i]=W2l[i];
  __syncthreads();

  int row = rb + wv;
  bool valid = (row <= TABN);
  int rowc = valid ? row : TABN;
  float d = (float)rowc * (RMAX/(float)TABN);
  float dsafe = fmaxf(d, 1e-9f);
  float inv = 1.0f/dsafe;
  float sc = sqrtf(2.0f/RMAX)*inv;
  float th = 3.14159265358979f*dsafe/RMAX;
  float s1 = sinf(th), cth = cosf(th);
  float basis[NB];
  {
    float skm = 0.0f, sk = s1, twoc = 2.0f*cth;
    #pragma unroll
    for (int k=0;k<NB;k++){
      basis[k] = sc*sk;
      float sn = twoc*sk - skm;
      skm = sk; sk = sn;
    }
  }
  float tt = fminf(d/RMAX, 1.0f-1e-6f);
  float env = (d < RMAX) ? exp2f(-1.44269504f*tt*tt/(1.0f-tt*tt)) : 0.0f;
  float h = 0.0f;
  #pragma unroll
  for (int b=0;b<NB;b++) h += basis[b]*sW1[b*FF + lane];
  sH[wv][lane] = softplus_f(h)*env*INV_AVG;
  __syncthreads();

  float o0=0.0f, o1=0.0f, o2=0.0f;
  #pragma unroll 8
  for (int k=0;k<FF;k++){
    float hk = sH[wv][k];
    const float* w = &sW2[k*192 + 3*lane];
    o0 += hk*w[0]; o1 += hk*w[1]; o2 += hk*w[2];
  }
  if (valid){
    unsigned short* dst = Tb + ((size_t)li*(TABN+1) + row)*192;
    dst[lane]       = f2bf(o0);
    dst[64 + lane]  = f2bf(o1);
    dst[128 + lane] = f2bf(o2);
  }
}

// ---------------- gather with table interpolation: per-node wave ----------------
__global__ __launch_bounds__(256) void k_gath(
  const float* __restrict__ Yb, const float* __restrict__ ub,
  const int* __restrict__ snds, const int* __restrict__ off,
  const float* __restrict__ x, const unsigned short* __restrict__ Tl,
  unsigned short* __restrict__ aggb, float* __restrict__ c0)
{
  int lane = threadIdx.x & 63, wv = threadIdx.x >> 6;
  int n = blockIdx.x*4 + wv;
  int js = off[n], je = off[n+1];
  float acc[SH];
  #pragma unroll
  for (int i=0;i<SH;i++) acc[i]=0.0f;
  for (int j=js;j<je;j++){
    float u = ub[j];
    int i = (int)u;
    float f = u - (float)i;
    const unsigned short* r = Tl + (size_t)i*192;
    float a0 = bf2f(r[lane]),     b0v = bf2f(r[192+lane]);
    float a1 = bf2f(r[64+lane]),  b1v = bf2f(r[256+lane]);
    float a2 = bf2f(r[128+lane]), b2v = bf2f(r[320+lane]);
    float o0 = a0 + f*(b0v-a0);
    float o1 = a1 + f*(b1v-a1);
    float o2 = a2 + f*(b2v-a2);
    float xs = x[(size_t)snds[j]*FF + lane];
    const float* y = Yb + (size_t)j*SH;
    float p0=o0*xs, p1=o1*xs, p2=o2*xs;
    acc[0]+=y[0]*p0;
    acc[1]+=y[1]*p1; acc[2]+=y[2]*p1; acc[3]+=y[3]*p1;
    acc[4]+=y[4]*p2; acc[5]+=y[5]*p2; acc[6]+=y[6]*p2;
    acc[7]+=y[7]*p2; acc[8]+=y[8]*p2;
  }
  unsigned short* db = aggb + (size_t)n*576 + lane*SH;
  #pragma unroll
  for (int i=0;i<SH;i++) db[i]=f2bf(acc[i]);
  c0[(size_t)n*FF + lane] = acc[0];
}

// ---------------- readout via MFMA: emb[:, colOff:+128] = aggb @ Wrp ----------------
__global__ __launch_bounds__(128) void k_read_mfma(
    const unsigned short* __restrict__ aggb, const unsigned short* __restrict__ Wrpl,
    float* __restrict__ emb, int colOff)
{
  int tid = threadIdx.x;
  int lane = tid & 63, wv = tid >> 6;
  int r0 = (blockIdx.x*2 + wv)*16;
  int mrow = lane & 15, kgrp = lane >> 4;
  float4v acc[8];
  #pragma unroll
  for (int t=0;t<8;t++){ acc[t][0]=0.f; acc[t][1]=0.f; acc[t][2]=0.f; acc[t][3]=0.f; }
  const unsigned short* arow = aggb + (size_t)(r0+mrow)*576 + kgrp*8;
  #pragma unroll 3
  for (int ks=0; ks<18; ++ks){
    short8v a = *(const short8v*)(arow + ks*32);
    #pragma unroll
    for (int t=0;t<8;t++){
      short8v b = *(const short8v*)(Wrpl + (((size_t)ks*8+t)*64 + lane)*8);
      acc[t] = __builtin_amdgcn_mfma_f32_16x16x32_bf16(a, b, acc[t], 0, 0, 0);
    }
  }
  #pragma unroll
  for (int t=0;t<8;t++){
    #pragma unroll
    for (int i=0;i<4;i++){
      emb[(size_t)(r0 + kgrp*4 + i)*256 + colOff + t*16 + mrow] = acc[t][i];
    }
  }
}

// ---------------- node update: x = silu(c0@W_upd + x@W_self) ----------------
__global__ __launch_bounds__(256) void k_upd(
    const float* __restrict__ c0, const float* __restrict__ xin,
    const float* __restrict__ Wu, const float* __restrict__ Wsf, float* __restrict__ xout)
{
  __shared__ float sWu[FF*FF], sWs[FF*FF];
  __shared__ float sA[4][FF], sX[4][FF];
  int t = threadIdx.x;
  for (int i=t;i<FF*FF;i+=256){ sWu[i]=Wu[i]; sWs[i]=Wsf[i]; }
  int lane = t&63, wv = t>>6;
  int n = blockIdx.x*4 + wv;
  sA[wv][lane] = c0[(size_t)n*FF + lane];
  sX[wv][lane] = xin[n*FF + lane];
  __syncthreads();
  float a=0.0f;
  #pragma unroll 8
  for (int k=0;k<FF;k++) a += sA[wv][k]*sWu[k*FF+lane] + sX[wv][k]*sWs[k*FF+lane];
  float sg = 1.0f/(1.0f+exp2f(-1.44269504f*a));
  xout[n*FF+lane] = a*sg;
}

// ---------------- merged heads: focus (0..2047) + species (2048..2079) + pos (2080..2207) ----------------
__global__ __launch_bounds__(256) void k_heads(
    const float* __restrict__ emb, const float* __restrict__ wf,
    const int* __restrict__ nnode, const int* __restrict__ tspec,
    const float* __restrict__ Ws1, const float* __restrict__ Ws2,
    const float* __restrict__ stab, const float* __restrict__ Wpos,
    float* __restrict__ outF, float* __restrict__ outSp, float* __restrict__ outPos)
{
  int b = blockIdx.x, t = threadIdx.x;
  if (b < 2048){
    int lane = t&63, wv = t>>6;
    int n = b*4 + wv;
    float a=0.0f;
    #pragma unroll
    for (int j=0;j<4;j++) a += emb[(size_t)n*256 + j*64 + lane]*wf[j*64+lane];
    #pragma unroll
    for (int off=32; off>0; off>>=1) a += __shfl_down(a, off, 64);
    if (lane==0) outF[n]=a;
  } else if (b < 2080){
    __shared__ float sf[256], sh2[128];
    int g = b - 2048;
    int fi = 0;
    for (int i=0;i<g;i++) fi += nnode[i];
    sf[t] = emb[(size_t)fi*256 + t];
    __syncthreads();
    if (t < 128){
      float a=0.0f;
      #pragma unroll 4
      for (int k=0;k<256;k++) a += sf[k]*Ws1[k*128+t];
      sh2[t] = softplus_f(a);
    }
    __syncthreads();
    if (t < 5){
      float a=0.0f;
      for (int k=0;k<128;k++) a += sh2[k]*Ws2[k*5+t];
      outSp[g*5+t]=a;
    }
  } else {
    __shared__ float ssp[256];
    int pb = b - 2080;
    int g = pb >> 2;
    int p = (pb & 3)*256 + t;
    int fi = 0;
    for (int i=0;i<g;i++) fi += nnode[i];
    int ts = tspec[g];
    ssp[t] = emb[(size_t)fi*256 + t]*stab[(size_t)ts*256 + t];
    __syncthreads();
    float a=0.0f;
    #pragma unroll 4
    for (int k=0;k<256;k++) a += ssp[k]*Wpos[(size_t)k*1024 + p];
    outPos[(size_t)g*1024 + p] = a;
  }
}

extern "C" void kernel_launch(void* const* d_in, const int* in_sizes, int n_in,
                              void* d_out, int out_size, void* d_ws, size_t ws_size,
                              hipStream_t stream)
{
  const float* positions = (const float*)d_in[0];
  const int*   species   = (const int*)  d_in[1];
  const int*   senders   = (const int*)  d_in[2];
  const int*   receivers = (const int*)  d_in[3];
  const int*   n_node    = (const int*)  d_in[4];
  const int*   tspec     = (const int*)  d_in[5];
  const float* emb_table = (const float*)d_in[6];
  const float* W1        = (const float*)d_in[7];
  const float* W2        = (const float*)d_in[8];
  const float* W_self    = (const float*)d_in[9];
  const float* W_upd     = (const float*)d_in[10];
  const float* W_read    = (const float*)d_in[11];
  const float* w_focus   = (const float*)d_in[12];
  const float* Ws1       = (const float*)d_in[13];
  const float* Ws2       = (const float*)d_in[14];
  const float* stab      = (const float*)d_in[15];
  const float* W_pos     = (const float*)d_in[16];

  char* base = (char*)d_ws;
  size_t ofs = 0;
  auto alloc = [&](size_t bytes)->char*{
    char* p = base + ofs;
    ofs = (ofs + bytes + 255) & ~(size_t)255;
    return p;
  };
  float* Yb   = (float*)alloc((size_t)EE*SH*4);      // sorted
  float* ub   = (float*)alloc((size_t)EE*4);         // sorted table coord
  int*   snds = (int*)  alloc((size_t)EE*4);         // sorted senders
  float* xA   = (float*)alloc((size_t)NN*FF*4);
  float* xB   = (float*)alloc((size_t)NN*FF*4);
  float* c0   = (float*)alloc((size_t)NN*FF*4);
  float* emb  = (float*)alloc((size_t)NN*256*4);
  int*   deg  = (int*)  alloc((size_t)NN*4);
  int*   off  = (int*)  alloc((size_t)(NN+1)*4);
  int*   cur  = (int*)  alloc((size_t)NN*4);
  int*   eidx = (int*)  alloc((size_t)EE*4);
  unsigned short* aggb = (unsigned short*)alloc((size_t)NN*576*2);
  unsigned short* Tb   = (unsigned short*)alloc((size_t)2*(TABN+1)*192*2);
  unsigned short* Wrp  = (unsigned short*)alloc((size_t)2*18*8*64*8*2);

  float* outFocus = (float*)d_out;
  float* outSp    = outFocus + NN;
  float* outPos   = outSp + GG*5;

  // CSR + prep + packs + table
  (void)hipMemsetAsync(deg, 0, NN*sizeof(int), stream);
  k_deg<<<EE/256,256,0,stream>>>(receivers,deg);
  k_scan<<<1,256,0,stream>>>(deg,off,cur);
  k_fill<<<EE/256,256,0,stream>>>(receivers,cur,eidx);
  k_prep<<<768,256,0,stream>>>(positions,senders,receivers,eidx,species,emb_table,
                               Yb,ub,snds,xA);
  k_pack<<<576,256,0,stream>>>(W_read,Wrp);
  k_tab<<<1026,256,0,stream>>>(W1,W2,Tb);

  // ---- layer 0 ----
  k_gath<<<NN/4,256,0,stream>>>(Yb,ub,snds,off,xA,Tb,aggb,c0);
  k_read_mfma<<<NN/32,128,0,stream>>>(aggb,Wrp,emb,0);
  k_upd<<<NN/4,256,0,stream>>>(c0,xA,W_upd,W_self,xB);

  // ---- layer 1 ----
  k_gath<<<NN/4,256,0,stream>>>(Yb,ub,snds,off,xB,Tb+(size_t)(TABN+1)*192,aggb,c0);
  k_read_mfma<<<NN/32,128,0,stream>>>(aggb,Wrp+(size_t)18*8*64*8,emb,DDIM);

  // ---- heads ----
  k_heads<<<2208,256,0,stream>>>(emb,w_focus,n_node,tspec,Ws1,Ws2,stab,W_pos,
                                 outFocus,outSp,outPos);
}